// Round 6
// baseline (406.397 us; speedup 1.0000x reference)
//
#include <hip/hip_runtime.h>

typedef unsigned short u16;
typedef unsigned int u32;
typedef __attribute__((ext_vector_type(8))) short short8;
typedef __attribute__((ext_vector_type(4))) short s16x4;
typedef __attribute__((ext_vector_type(4))) float f32x4;

// async global->LDS, 16B per lane; LDS dst = wave-uniform base + lane*16
#define ASYNC_CP16(gsrc, ldst) \
  __builtin_amdgcn_global_load_lds((__attribute__((address_space(1))) void*)(gsrc), \
                                   (__attribute__((address_space(3))) void*)(ldst), 16, 0, 0)

// 16x16x16 bf16 MFMA: B-frag lane-map == C/D lane-map -> direct P chaining
#if __has_builtin(__builtin_amdgcn_mfma_f32_16x16x16bf16_1k)
#define MFMA16(A, B, C) __builtin_amdgcn_mfma_f32_16x16x16bf16_1k(A, B, C, 0, 0, 0)
#elif __has_builtin(__builtin_amdgcn_mfma_f32_16x16x16_bf16)
#define MFMA16(A, B, C) __builtin_amdgcn_mfma_f32_16x16x16_bf16(A, B, C, 0, 0, 0)
#else
static __device__ __forceinline__ f32x4 mfma16_asm(s16x4 a, s16x4 b, f32x4 c) {
  asm("v_mfma_f32_16x16x16_bf16 %0, %1, %2, %0" : "+v"(c) : "v"(a), "v"(b));
  return c;
}
#define MFMA16(A, B, C) mfma16_asm(A, B, C)
#endif

static __device__ __forceinline__ u16 f2bf(float f) {
  u32 u = __builtin_bit_cast(u32, f);
  u = u + 0x7fffu + ((u >> 16) & 1u);   // RNE
  return (u16)(u >> 16);
}
static __device__ __forceinline__ u32 pk2(float a, float b) {
  return (u32)f2bf(a) | ((u32)f2bf(b) << 16);
}
// fast pack: round-half-up then v_perm_b32 grabs the two high halves (3 VALU ops)
static __device__ __forceinline__ u32 pk2r(float a, float b) {
  u32 ua = __builtin_bit_cast(u32, a) + 0x8000u;
  u32 ub = __builtin_bit_cast(u32, b) + 0x8000u;
  return __builtin_amdgcn_perm(ub, ua, 0x07060302);  // [ua.b2,ua.b3,ub.b2,ub.b3]
}

// ---------------------------------------------------------------------------
// Kernel 0: fp32 -> bf16 conversion into ws.
// ---------------------------------------------------------------------------
__global__ __launch_bounds__(256) void convert_all(
    const float* __restrict__ xq, const float* __restrict__ xkv,
    const float* __restrict__ wq, const float* __restrict__ wk,
    const float* __restrict__ wv, const float* __restrict__ wo,
    u16* __restrict__ dst)
{
  long i = ((long)blockIdx.x * 256 + threadIdx.x) * 4;
  const float* s; long o;
  if      (i < 8388608)  { s = xq;  o = i; }
  else if (i < 16777216) { s = xkv; o = i - 8388608; }
  else if (i < 17825792) { s = wq;  o = i - 16777216; }
  else if (i < 18874368) { s = wk;  o = i - 17825792; }
  else if (i < 19922944) { s = wv;  o = i - 18874368; }
  else                   { s = wo;  o = i - 19922944; }
  float4 v = *(const float4*)(s + o);
  uint2 pkv; pkv.x = pk2(v.x, v.y); pkv.y = pk2(v.z, v.w);
  *(uint2*)(dst + i) = pkv;
}

// ---------------------------------------------------------------------------
// GEMM: y[t][d] = sum_k x[t][k] W[d][k] + bias[d]   (m97 structure)
// For z=0,1 and EPI=1 the MFMA operands are swapped (af <- W tile), so the
// C-tile has rows=d, cols=token -> per-lane 4 consecutive d -> contiguous
// uint2/float4 epilogue stores. z=2 keeps rows=token (keys pair-contiguous).
//   z=0: Q * (0.125*log2e), layout [bh][n][64]
//   z=1: K chunked  [bh][kt][dblk=8][key=128][8]
//   z=2: V 32-key groups [bh][kt][g=4][d=64][32], inner 32 = interleaved
//        (key&3) + ((key>>4)&1)*4 + (((key>>2)&3) ^ ((d>>1)&3))*8
// EPI=1: output projection; fp32 [tok][1024] via float4 stores.
// ---------------------------------------------------------------------------
template<int EPI>
__global__ __launch_bounds__(256)
void gemm_k(const u16* __restrict__ Axq, const u16* __restrict__ Axkv,
            const u16* __restrict__ W0, const u16* __restrict__ W1, const u16* __restrict__ W2,
            const float* __restrict__ b0, const float* __restrict__ b1, const float* __restrict__ b2,
            u16* __restrict__ Qo, u16* __restrict__ Ko, u16* __restrict__ Vo,
            float* __restrict__ Fo)
{
  __shared__ u16 lsa[128*32];
  __shared__ u16 lsb[128*32];
  const int tid = threadIdx.x;
  const int w = tid >> 6, lane = tid & 63;
  const int wr = w >> 1, wc = w & 1;
  const int bm = blockIdx.x, bn = blockIdx.y, z = blockIdx.z;
  const int l15 = lane & 15, l4 = lane >> 4;

  const u16* A; const u16* W; const float* bias;
  if (EPI == 0) {
    A    = (z == 0) ? Axq : Axkv;
    W    = (z == 0) ? W0 : (z == 1) ? W1 : W2;
    bias = (z == 0) ? b0 : (z == 1) ? b1 : b2;
  } else {
    A = Axq; W = W0; bias = b0;
  }
  const u16* Ag = A + (long)bm*128*1024;
  const u16* Wg = W + (long)bn*128*1024;

  const bool swapop = (EPI == 1) || (z != 2);
  const u16* pAs = swapop ? lsb : lsa;   // af source (rows of C)
  const u16* pBs = swapop ? lsa : lsb;   // bfr source (cols of C)

  f32x4 acc[4][4];
#pragma unroll
  for (int i = 0; i < 4; ++i)
#pragma unroll
    for (int j = 0; j < 4; ++j)
      acc[i][j] = (f32x4){0.f,0.f,0.f,0.f};

  for (int k0 = 0; k0 < 1024; k0 += 32) {
    __syncthreads();
#pragma unroll
    for (int c = 0; c < 2; ++c) {
      int tp = c*256 + tid;
      int row = tp >> 2, col = (tp & 3) * 8;
      ASYNC_CP16(Ag + (long)row*1024 + k0 + col, &lsa[tp*8]);
      ASYNC_CP16(Wg + (long)row*1024 + k0 + col, &lsb[tp*8]);
    }
    __syncthreads();
    short8 af[4], bfr[4];
#pragma unroll
    for (int i = 0; i < 4; ++i)
      af[i] = *(const short8*)&pAs[(wr*64 + i*16 + l15)*32 + l4*8];
#pragma unroll
    for (int j = 0; j < 4; ++j)
      bfr[j] = *(const short8*)&pBs[(wc*64 + j*16 + l15)*32 + l4*8];
#pragma unroll
    for (int i = 0; i < 4; ++i)
#pragma unroll
      for (int j = 0; j < 4; ++j)
        acc[i][j] = __builtin_amdgcn_mfma_f32_16x16x32_bf16(af[i], bfr[j], acc[i][j], 0, 0, 0);
  }

  if (swapop) {   // rows = d, cols = token
#pragma unroll
    for (int i = 0; i < 4; ++i) {
      const int dg = bn*128 + wr*64 + i*16 + l4*4;
      const float4 b4 = *(const float4*)&bias[dg];
#pragma unroll
      for (int j = 0; j < 4; ++j) {
        const int tk = bm*128 + wc*64 + j*16 + l15;
        const float v0 = acc[i][j][0] + b4.x, v1 = acc[i][j][1] + b4.y;
        const float v2 = acc[i][j][2] + b4.z, v3 = acc[i][j][3] + b4.w;
        if (EPI == 1) {
          *(float4*)&Fo[(long)tk*1024 + dg] = (float4){v0, v1, v2, v3};
        } else if (z == 0) {
          const int bb_ = tk >> 11, n = tk & 2047, h = dg >> 6, c0 = dg & 63;
          uint2 pv;
          pv.x = pk2(v0*0.18033688f, v1*0.18033688f);
          pv.y = pk2(v2*0.18033688f, v3*0.18033688f);
          *(uint2*)&Qo[((long)(bb_*16 + h)*2048 + n)*64 + c0] = pv;
        } else {  // z == 1: K chunked
          const int bb_ = tk >> 11, n = tk & 2047, h = dg >> 6, d0 = dg & 63;
          const long base = (long)(bb_*16 + h)*131072 + (long)(n >> 7)*8192
                          + (d0 >> 3)*1024 + (n & 127)*8 + (d0 & 7);
          uint2 pv; pv.x = pk2(v0, v1); pv.y = pk2(v2, v3);
          *(uint2*)&Ko[base] = pv;
        }
      }
    }
  } else {        // z == 2: rows = token(key), cols = d
#pragma unroll
    for (int j = 0; j < 4; ++j) {
      const int colg = bn*128 + wc*64 + j*16 + l15;
      const float bb = bias[colg];
      const int h = colg >> 6, c = colg & 63;
#pragma unroll
      for (int i = 0; i < 4; ++i) {
        const int rowg = bm*128 + wr*64 + i*16 + l4*4;
        const int bb_ = rowg >> 11, n0 = rowg & 2047;
        const long base = (long)(bb_*16 + h)*131072 + (long)(n0 >> 7)*8192
                        + ((n0 & 127) >> 5)*2048 + (long)c*32
                        + ((n0 >> 4) & 1)*4 + ((((n0 >> 2) & 3) ^ ((c >> 1) & 3)))*8;
        uint2 pv;
        pv.x = pk2(acc[i][j][0] + bb, acc[i][j][1] + bb);
        pv.y = pk2(acc[i][j][2] + bb, acc[i][j][3] + bb);
        *(uint2*)&Vo[base] = pv;
      }
    }
  }
}

// ---------------------------------------------------------------------------
// Flash attention, causal, S^T orientation, no online max, direct P->PV
// register chaining via MFMA16. Block = 128 queries (4 waves x 2 qsets of 16).
// Grid (16, 64). K-tile = 128 keys. On the diagonal tile, fully-masked
// 16-key tiles are skipped via wave-uniform guards; only tile nt=2w+c is
// partial, mask condition l4*4+r > l15 (kt-independent).
// ---------------------------------------------------------------------------
template<bool LAST>
static __device__ __forceinline__ void attn_step(
    const u16* __restrict__ Kh, const u16* __restrict__ Vh, long kt,
    u16* lk, u16* lv, int tid, int w, int l4, int l15,
    const short8 (&qf)[2][2], f32x4 (&o)[2][4], float (&rs)[2])
{
  __syncthreads();
#pragma unroll
  for (int c2 = 0; c2 < 4; ++c2) {
    int tp = c2*256 + tid;
    ASYNC_CP16(Kh + kt*8192 + tp*8, &lk[tp*8]);
    ASYNC_CP16(Vh + kt*8192 + tp*8, &lv[tp*8]);
  }
  __syncthreads();

  s16x4 pkv[2][8];
#pragma unroll
  for (int c = 0; c < 2; ++c) {
    const int ntl = 2*w + c;
    f32x4 s[8];
#pragma unroll
    for (int nt = 0; nt < 8; ++nt) {
      if (!LAST || nt <= ntl) {
        f32x4 a = (f32x4){0.f,0.f,0.f,0.f};
#pragma unroll
        for (int ks = 0; ks < 2; ++ks) {
          short8 kf = *(const short8*)&lk[(ks*4 + l4)*1024 + (nt*16 + l15)*8];
          a = __builtin_amdgcn_mfma_f32_16x16x32_bf16(kf, qf[c][ks], a, 0, 0, 0);
        }
        s[nt] = a;
      }
    }
    if (LAST) {
#pragma unroll
      for (int r = 0; r < 4; ++r)
        if (l4*4 + r > l15) s[ntl][r] = -1e30f;
    }
#pragma unroll
    for (int nt = 0; nt < 8; ++nt) {
      if (!LAST || nt <= ntl) {
        float p0 = __builtin_amdgcn_exp2f(s[nt][0]);
        float p1 = __builtin_amdgcn_exp2f(s[nt][1]);
        float p2 = __builtin_amdgcn_exp2f(s[nt][2]);
        float p3 = __builtin_amdgcn_exp2f(s[nt][3]);
        rs[c] += (p0 + p1) + (p2 + p3);
        union { uint2 u; s16x4 v; } pu;
        pu.u.x = pk2r(p0, p1);
        pu.u.y = pk2r(p2, p3);
        pkv[c][nt] = pu.v;
      }
    }
  }

  const int swz = l4 ^ ((l15 >> 1) & 3);
#pragma unroll
  for (int g = 0; g < 4; ++g) {
    if (!LAST || 2*g <= 2*w + 1) {
#pragma unroll
      for (int ntd = 0; ntd < 4; ++ntd) {
        short8 vv = *(const short8*)&lv[g*2048 + (ntd*16 + l15)*32 + swz*8];
        s16x4 v0 = __builtin_shufflevector(vv, vv, 0, 1, 2, 3);
        s16x4 v1 = __builtin_shufflevector(vv, vv, 4, 5, 6, 7);
#pragma unroll
        for (int c = 0; c < 2; ++c) {
          const int ntl = 2*w + c;
          if (!LAST || 2*g <= ntl)     o[c][ntd] = MFMA16(v0, pkv[c][2*g],     o[c][ntd]);
          if (!LAST || 2*g + 1 <= ntl) o[c][ntd] = MFMA16(v1, pkv[c][2*g + 1], o[c][ntd]);
        }
      }
    }
  }
}

__global__ __launch_bounds__(256)
void attn_k(const u16* __restrict__ Q, const u16* __restrict__ K,
            const u16* __restrict__ V, u16* __restrict__ AO)
{
  __shared__ u16 lk[8192];   // K tile [dblk 8][key 128][8]
  __shared__ u16 lv[8192];   // V tile [g 4][d 64][32 interleaved]
  const int tid = threadIdx.x;
  const int w = tid >> 6, lane = tid & 63;
  const int l15 = lane & 15, l4 = lane >> 4;
  const int qt = 15 - blockIdx.x;          // heavy blocks first
  const int bh = blockIdx.y;
  const int q0 = qt*128, qbase = q0 + w*32;
  const u16* Qh = Q + (long)bh*131072;
  const u16* Kh = K + (long)bh*131072;
  const u16* Vh = V + (long)bh*131072;

  short8 qf[2][2];
#pragma unroll
  for (int c = 0; c < 2; ++c)
#pragma unroll
    for (int ks = 0; ks < 2; ++ks)
      qf[c][ks] = *(const short8*)&Qh[(long)(qbase + c*16 + l15)*64 + ks*32 + l4*8];

  f32x4 o[2][4];
#pragma unroll
  for (int c = 0; c < 2; ++c)
#pragma unroll
    for (int nt = 0; nt < 4; ++nt) o[c][nt] = (f32x4){0.f,0.f,0.f,0.f};
  float rs[2] = {0.f, 0.f};

  for (int kt = 0; kt < qt; ++kt)
    attn_step<false>(Kh, Vh, kt, lk, lv, tid, w, l4, l15, qf, o, rs);
  attn_step<true>(Kh, Vh, qt, lk, lv, tid, w, l4, l15, qf, o, rs);

  const int b = bh >> 4, h = bh & 15;
#pragma unroll
  for (int c = 0; c < 2; ++c) {
    float t = rs[c];
    t += __shfl_xor(t, 16, 64);
    t += __shfl_xor(t, 32, 64);
    const float inv = 1.0f / t;
    const long tok = (long)b*2048 + qbase + c*16 + l15;
#pragma unroll
    for (int ntd = 0; ntd < 4; ++ntd) {
      uint2 pv;
      pv.x = pk2(o[c][ntd][0]*inv, o[c][ntd][1]*inv);
      pv.y = pk2(o[c][ntd][2]*inv, o[c][ntd][3]*inv);
      *(uint2*)&AO[tok*1024 + h*64 + ntd*16 + l4*4] = pv;
    }
  }
}

// ---------------------------------------------------------------------------
extern "C" void kernel_launch(void* const* d_in, const int* in_sizes, int n_in,
                              void* d_out, int out_size, void* d_ws, size_t ws_size,
                              hipStream_t stream)
{
  const float* xq  = (const float*)d_in[0];
  const float* xkv = (const float*)d_in[1];
  const float* Wq  = (const float*)d_in[2];
  const float* bq  = (const float*)d_in[3];
  const float* Wk  = (const float*)d_in[4];
  const float* bk  = (const float*)d_in[5];
  const float* Wv  = (const float*)d_in[6];
  const float* bv  = (const float*)d_in[7];
  const float* Wo  = (const float*)d_in[8];
  const float* bo  = (const float*)d_in[9];

  u16* ws    = (u16*)d_ws;
  u16* xq_b  = ws;                    // 8M bf16
  u16* xkv_b = xq_b  + (1l<<23);      // 8M
  u16* wq_b  = xkv_b + (1l<<23);      // 1M
  u16* wk_b  = wq_b  + (1l<<20);
  u16* wv_b  = wk_b  + (1l<<20);
  u16* wo_b  = wv_b  + (1l<<20);
  u16* Qb    = wo_b  + (1l<<20);      // 8M, [bh][n][64], scaled 0.125*log2e
  u16* Kb    = Qb    + (1l<<23);      // 8M, [bh][kt][dblk][key][8]
  u16* Vb    = Kb    + (1l<<23);      // 8M, [bh][kt][g][d][32]
  u16* Ab    = Vb    + (1l<<23);      // 8M, [tok][1024]

  convert_all<<<20480, 256, 0, stream>>>(xq, xkv, Wq, Wk, Wv, Wo, ws);
  gemm_k<0><<<dim3(64,8,3), 256, 0, stream>>>(xq_b, xkv_b, wq_b, wk_b, wv_b,
                                              bq, bk, bv, Qb, Kb, Vb, nullptr);
  attn_k<<<dim3(16,64), 256, 0, stream>>>(Qb, Kb, Vb, Ab);
  gemm_k<1><<<dim3(64,8,1), 256, 0, stream>>>(Ab, nullptr, wo_b, nullptr, nullptr,
                                              bo, nullptr, nullptr,
                                              nullptr, nullptr, nullptr,
                                              (float*)d_out);
}